// Round 3
// baseline (201.816 us; speedup 1.0000x reference)
//
#include <hip/hip_runtime.h>
#include <math.h>

typedef short   s16x8  __attribute__((ext_vector_type(8)));
typedef __bf16  bf16x8 __attribute__((ext_vector_type(8)));
typedef float   f32x4  __attribute__((ext_vector_type(4)));

#define T_FREQ 169
#define NN     336      // L == n (output length)
#define CCH    512
#define BB     32
#define TP     176      // t padded to 11*16 (stage A M)
#define LP     352      // L padded to 11*32 (stage A K)
#define KP     192      // t padded to 6*32  (stage C K)

// ---- workspace layout (bytes), all offsets 16B-aligned ----
static constexpr size_t OFF_COEF = 0;                                  // 169 f32
static constexpr size_t OFF_FC   = 1024;                               // [176][352] bf16 (cos/sqrt(n))
static constexpr size_t OFF_FS   = OFF_FC + 124928;                    // [176][352] bf16 (-sin/sqrt(n))
static constexpr size_t OFF_CCOS = OFF_FS + 124928;                    // [336][192] bf16 cos
static constexpr size_t OFF_CSIN = OFF_CCOS + 130048;                  // [336][192] bf16 -sin
static constexpr size_t OFF_XT   = OFF_CSIN + 130048;                  // [32][512][352] bf16 (x transposed)
static constexpr size_t OFF_XR   = OFF_XT + (size_t)BB*CCH*LP*2;       // [176][32][512] bf16
static constexpr size_t OFF_XI   = OFF_XR + (size_t)TP*BB*CCH*2;       // [176][32][512] bf16
static constexpr size_t OFF_YR   = OFF_XI + (size_t)TP*BB*CCH*2;       // [32][192][512] bf16 (as u16)
static constexpr size_t OFF_YI   = OFF_YR + (size_t)BB*KP*CCH*2;       // [32][192][512] bf16 (as u16)

__device__ __forceinline__ unsigned short f2bf(float f){
  return __builtin_bit_cast(unsigned short, (__bf16)f);
}

__device__ __forceinline__ bf16x8 cvt8(float4 lo, float4 hi){
  bf16x8 r;
  r[0]=(__bf16)lo.x; r[1]=(__bf16)lo.y; r[2]=(__bf16)lo.z; r[3]=(__bf16)lo.w;
  r[4]=(__bf16)hi.x; r[5]=(__bf16)hi.y; r[6]=(__bf16)hi.z; r[7]=(__bf16)hi.w;
  return r;
}

__device__ __forceinline__ f32x4 mfma16(bf16x8 a, bf16x8 b, f32x4 c){
  return __builtin_amdgcn_mfma_f32_16x16x32_bf16(a, b, c, 0, 0, 0);
}

// ---------------- P1: coef softmax + twiddle tables ----------------
__global__ __launch_bounds__(256) void prep_tables(const float* __restrict__ wts, char* ws){
  float* coef = (float*)(ws + OFF_COEF);
  unsigned short* Fc  = (unsigned short*)(ws + OFF_FC);
  unsigned short* Fs  = (unsigned short*)(ws + OFF_FS);
  unsigned short* Cc  = (unsigned short*)(ws + OFF_CCOS);
  unsigned short* Cs  = (unsigned short*)(ws + OFF_CSIN);
  const float PI2_N = 6.283185307179586f / (float)NN;
  const float inv_sqrt_n = 0.05455447255899809f;  // 1/sqrt(336)

  if (blockIdx.x == 0){
    __shared__ float red[256];
    int tid = threadIdx.x;
    float v = (tid < T_FREQ) ? wts[tid] : -1e30f;
    red[tid] = v; __syncthreads();
    for (int s = 128; s > 0; s >>= 1){ if (tid < s) red[tid] = fmaxf(red[tid], red[tid+s]); __syncthreads(); }
    float mx = red[0]; __syncthreads();
    float e = (tid < T_FREQ) ? expf(v - mx) : 0.f;
    red[tid] = e; __syncthreads();
    for (int s = 128; s > 0; s >>= 1){ if (tid < s) red[tid] += red[tid+s]; __syncthreads(); }
    float ssum = red[0];
    if (tid < T_FREQ){
      float sc = (tid == 0 || tid == T_FREQ-1) ? 1.f : 2.f;
      coef[tid] = (e / ssum) * sc * inv_sqrt_n;
    }
    return;
  }
  int gid = (blockIdx.x - 1) * 256 + threadIdx.x;
  int stride = (gridDim.x - 1) * 256;
  for (int e = gid; e < TP*LP; e += stride){
    int i = e / LP, l = e % LP;
    float c = 0.f, s = 0.f;
    if (l < NN){
      int m = (i * l) % NN;
      float sv, cv; sincosf(PI2_N * (float)m, &sv, &cv);
      c = cv * inv_sqrt_n; s = -sv * inv_sqrt_n;
    }
    Fc[e] = f2bf(c); Fs[e] = f2bf(s);
  }
  for (int e = gid; e < NN*KP; e += stride){
    int l = e / KP, i = e % KP;
    float c = 0.f, s = 0.f;
    if (i < T_FREQ){
      int m = (i * l) % NN;
      float sv, cv; sincosf(PI2_N * (float)m, &sv, &cv);
      c = cv; s = -sv;
    }
    Cc[e] = f2bf(c); Cs[e] = f2bf(s);
  }
}

// ---------------- P2: x [b][l][c] f32 -> x_t [b][c][l] bf16 (l zero-padded to 352) ----------------
__global__ __launch_bounds__(256) void transpose_x(const float* __restrict__ x, char* ws){
  unsigned short* xt = (unsigned short*)(ws + OFF_XT);
  __shared__ float tile[32][33];
  int bid = blockIdx.x;
  int b  = bid / (11*16);
  int rm = bid % (11*16);
  int lt = rm / 16, ct = rm % 16;
  int tx = threadIdx.x & 31, ty = threadIdx.x >> 5;   // 32 x 8
  #pragma unroll
  for (int k = 0; k < 4; ++k){
    int l = lt*32 + ty + k*8;
    int c = ct*32 + tx;
    float v = (l < NN) ? x[((size_t)b*NN + l)*CCH + c] : 0.f;
    tile[ty + k*8][tx] = v;
  }
  __syncthreads();
  #pragma unroll
  for (int k = 0; k < 4; ++k){
    int crow = ct*32 + ty + k*8;
    int lcol = lt*32 + tx;
    xt[((size_t)b*CCH + crow)*LP + lcol] = f2bf(tile[tx][ty + k*8]);
  }
}

// ---------------- Stage A: rfft as GEMM, M-split 2-way ----------------
__global__ __launch_bounds__(256) void stage_rfft(char* ws){
  const unsigned short* xt = (const unsigned short*)(ws + OFF_XT);
  const unsigned short* Fc = (const unsigned short*)(ws + OFF_FC);
  const unsigned short* Fs = (const unsigned short*)(ws + OFF_FS);
  unsigned short* xr = (unsigned short*)(ws + OFF_XR);
  unsigned short* xi = (unsigned short*)(ws + OFF_XI);

  int bid = blockIdx.x;
  int b  = bid >> 4;
  int rm = bid & 15;
  int c0 = (rm & 7) * 64;
  int mh = rm >> 3;
  int mbase = mh * 5;                 // tiles mbase..mbase+5; tile 5 duplicated (identical writes)
  int tid = threadIdx.x, lane = tid & 63, wv = tid >> 6;
  int kg = lane >> 4, ln = lane & 15;
  int c = c0 + wv*16 + ln;

  f32x4 aR[6], aI[6];
  #pragma unroll
  for (int m = 0; m < 6; ++m){ aR[m] = (f32x4){0,0,0,0}; aI[m] = (f32x4){0,0,0,0}; }

  const unsigned short* xrow = xt + ((size_t)b*CCH + c)*LP;
  for (int kk = 0; kk < 11; ++kk){
    int ko = kk*32 + kg*8;
    bf16x8 bx = *(const bf16x8*)(xrow + ko);
    #pragma unroll
    for (int m = 0; m < 6; ++m){
      bf16x8 fc = *(const bf16x8*)(Fc + (size_t)((mbase+m)*16 + ln)*LP + ko);
      bf16x8 fs = *(const bf16x8*)(Fs + (size_t)((mbase+m)*16 + ln)*LP + ko);
      aR[m] = mfma16(fc, bx, aR[m]);
      aI[m] = mfma16(fs, bx, aI[m]);
    }
  }
  int rbase = kg*4;
  #pragma unroll
  for (int m = 0; m < 6; ++m){
    #pragma unroll
    for (int r = 0; r < 4; ++r){
      int i = (mbase+m)*16 + rbase + r;
      size_t off = ((size_t)i*BB + b)*CCH + c;
      xr[off] = f2bf(aR[m][r]);
      xi[off] = f2bf(aI[m][r]);
    }
  }
}

// ---------------- Stage B v3: block-contiguous W stream -> bf16 LDS (swizzled) -> MFMA ----------------
// Block = (freq i, 16-out tile ot). Grid 169*32 = 5408. 4 waves: (mb = batch-half, part = R/I).
__global__ __launch_bounds__(256, 4) void stage_cgemm(const float* __restrict__ Wr, const float* __restrict__ Wi,
                                                      const float* __restrict__ br, const float* __restrict__ bi,
                                                      char* ws){
  const unsigned short* xr = (const unsigned short*)(ws + OFF_XR);
  const unsigned short* xi = (const unsigned short*)(ws + OFF_XI);
  const float* coef = (const float*)(ws + OFF_COEF);
  unsigned short* yr = (unsigned short*)(ws + OFF_YR);
  unsigned short* yi = (unsigned short*)(ws + OFF_YI);

  __shared__ unsigned short sW[2][16*CCH];   // bf16 [h][row][k], k-granules XOR-swizzled per row

  int bid = blockIdx.x;
  int i  = bid >> 5;
  int ot = bid & 31;
  int tid = threadIdx.x, lane = tid & 63, wv = tid >> 6;
  int kg = lane >> 4, ln = lane & 15;

  // ---- stage: Wr/Wi rows [ot*16, ot*16+16) x all 512 k — two contiguous 32 KB streams ----
  const float* gWr = Wr + ((size_t)i*CCH + ot*16)*CCH;
  const float* gWi = Wi + ((size_t)i*CCH + ot*16)*CCH;
  float4 buf[16];
  #pragma unroll
  for (int j = 0; j < 4; ++j){
    int row = j*4 + wv;
    const float* s = gWr + (size_t)row*CCH + lane*8;
    buf[2*j]   = *(const float4*)(s);
    buf[2*j+1] = *(const float4*)(s + 4);
  }
  #pragma unroll
  for (int j = 0; j < 4; ++j){
    int row = j*4 + wv;
    const float* s = gWi + (size_t)row*CCH + lane*8;
    buf[8+2*j]   = *(const float4*)(s);
    buf[8+2*j+1] = *(const float4*)(s + 4);
  }
  #pragma unroll
  for (int j = 0; j < 4; ++j){
    int row = j*4 + wv;
    int dst = row*CCH + ((lane ^ (row & 7)) << 3);      // k8-granule = lane, XOR-swizzled
    *(bf16x8*)&sW[0][dst] = cvt8(buf[2*j],   buf[2*j+1]);
    *(bf16x8*)&sW[1][dst] = cvt8(buf[8+2*j], buf[8+2*j+1]);
  }
  __syncthreads();

  // ---- compute: acc over K=512, 2 MFMA per 32-k step ----
  int mb = wv & 1, part = wv >> 1;
  f32x4 acc = (f32x4){0,0,0,0};
  const unsigned short* xa = xr + (size_t)(i*BB + mb*16 + ln)*CCH;
  const unsigned short* xb = xi + (size_t)(i*BB + mb*16 + ln)*CCH;

  #pragma unroll
  for (int kk = 0; kk < 16; ++kk){
    int ko = kk*32 + kg*8;
    bf16x8 ar = *(const bf16x8*)(xa + ko);
    bf16x8 ai = *(const bf16x8*)(xb + ko);
    int g = (((kk*4 + kg) ^ (ln & 7)) << 3);
    bf16x8 wr8 = *(const bf16x8*)&sW[0][ln*CCH + g];
    bf16x8 wi8 = *(const bf16x8*)&sW[1][ln*CCH + g];
    bf16x8 nwi = __builtin_bit_cast(bf16x8, (s16x8)(__builtin_bit_cast(s16x8, wi8) ^ (short)0x8000));
    bf16x8 b1 = part ? wi8 : wr8;
    bf16x8 b2 = part ? wr8 : nwi;
    acc = mfma16(ar, b1, acc);     // part R: xr*Wr   | part I: xr*Wi
    acc = mfma16(ai, b2, acc);     // part R: -xi*Wi  | part I: xi*Wr
  }

  int o = ot*16 + ln;
  float cf = coef[i];
  float bias = (part ? bi : br)[(size_t)i*CCH + o];
  unsigned short* yp = part ? yi : yr;
  #pragma unroll
  for (int r = 0; r < 4; ++r){
    int bb = mb*16 + kg*4 + r;
    yp[((size_t)bb*KP + i)*CCH + o] = f2bf((acc[r] + bias) * cf);
  }
}

// ---------------- Stage C: irfft projection, M-split 2-way ----------------
__global__ __launch_bounds__(256) void stage_irfft(const char* ws_c, float* __restrict__ out){
  const char* ws = ws_c;
  const unsigned short* Cc = (const unsigned short*)(ws + OFF_CCOS);
  const unsigned short* Cs = (const unsigned short*)(ws + OFF_CSIN);
  const unsigned short* yr = (const unsigned short*)(ws + OFF_YR);
  const unsigned short* yi = (const unsigned short*)(ws + OFF_YI);

  __shared__ unsigned short lr[64][40];
  __shared__ unsigned short li[64][40];

  int bid = blockIdx.x;
  int b  = bid >> 4;
  int rm = bid & 15;
  int c0 = (rm & 7) * 64;
  int mh = rm >> 3;
  int mbase = mh * 10;                // tiles mbase..mbase+10; tile 10 duplicated (identical writes)
  int tid = threadIdx.x, lane = tid & 63, wv = tid >> 6;
  int kg = lane >> 4, ln = lane & 15;

  f32x4 acc[11];
  #pragma unroll
  for (int m = 0; m < 11; ++m) acc[m] = (f32x4){0,0,0,0};

  for (int kk = 0; kk < 6; ++kk){
    if (kk) __syncthreads();
    #pragma unroll
    for (int q = 0; q < 8; ++q){
      int idx = q*256 + tid;
      int ir = idx >> 6, cc = idx & 63;
      int i = kk*32 + ir;
      unsigned short vr = 0, vi = 0;
      if (i < T_FREQ){
        size_t off = ((size_t)b*KP + i)*CCH + c0 + cc;
        vr = yr[off]; vi = yi[off];
      }
      lr[cc][ir] = vr;
      li[cc][ir] = vi;
    }
    __syncthreads();
    int ko = kk*32 + kg*8;
    bf16x8 blr = *(const bf16x8*)(&lr[wv*16 + ln][kg*8]);
    bf16x8 bli = *(const bf16x8*)(&li[wv*16 + ln][kg*8]);
    #pragma unroll
    for (int m = 0; m < 11; ++m){
      bf16x8 ac = *(const bf16x8*)(Cc + (size_t)((mbase+m)*16 + ln)*KP + ko);
      bf16x8 as = *(const bf16x8*)(Cs + (size_t)((mbase+m)*16 + ln)*KP + ko);
      acc[m] = mfma16(ac, blr, acc[m]);
      acc[m] = mfma16(as, bli, acc[m]);
    }
  }

  int cdst = c0 + wv*16 + ln;
  #pragma unroll
  for (int m = 0; m < 11; ++m){
    #pragma unroll
    for (int r = 0; r < 4; ++r){
      int l = (mbase+m)*16 + kg*4 + r;
      out[((size_t)b*NN + l)*CCH + cdst] = acc[m][r];
    }
  }
}

extern "C" void kernel_launch(void* const* d_in, const int* in_sizes, int n_in,
                              void* d_out, int out_size, void* d_ws, size_t ws_size,
                              hipStream_t stream){
  const float* x   = (const float*)d_in[0];
  const float* Wr  = (const float*)d_in[1];
  const float* Wi  = (const float*)d_in[2];
  const float* br  = (const float*)d_in[3];
  const float* bi  = (const float*)d_in[4];
  const float* wts = (const float*)d_in[5];
  char* ws = (char*)d_ws;

  prep_tables<<<257, 256, 0, stream>>>(wts, ws);
  transpose_x<<<32*11*16, 256, 0, stream>>>(x, ws);
  stage_rfft<<<512, 256, 0, stream>>>(ws);
  stage_cgemm<<<T_FREQ*32, 256, 0, stream>>>(Wr, Wi, br, bi, ws);
  stage_irfft<<<512, 256, 0, stream>>>(ws, (float*)d_out);
}

// Round 4
// 195.869 us; speedup vs baseline: 1.0304x; 1.0304x over previous
//
#include <hip/hip_runtime.h>
#include <math.h>

typedef short   s16x8  __attribute__((ext_vector_type(8)));
typedef __bf16  bf16x8 __attribute__((ext_vector_type(8)));
typedef float   f32x4  __attribute__((ext_vector_type(4)));

#define T_FREQ 169
#define NN     336      // L == n (output length)
#define CCH    512
#define BB     32
#define TP     176      // t padded to 11*16 (stage A M)
#define LP     352      // L padded to 11*32 (stage A K)
#define KP     192      // t padded to 6*32  (stage C K)
#define QK     128      // K per staged quarter in stage_cgemm

// ---- workspace layout (bytes), all offsets 16B-aligned ----
static constexpr size_t OFF_COEF = 0;                                  // 169 f32
static constexpr size_t OFF_FC   = 1024;                               // [176][352] bf16 (cos/sqrt(n))
static constexpr size_t OFF_FS   = OFF_FC + 124928;                    // [176][352] bf16 (-sin/sqrt(n))
static constexpr size_t OFF_CCOS = OFF_FS + 124928;                    // [336][192] bf16 cos
static constexpr size_t OFF_CSIN = OFF_CCOS + 130048;                  // [336][192] bf16 -sin
static constexpr size_t OFF_XT   = OFF_CSIN + 130048;                  // [32][512][352] bf16 (x transposed)
static constexpr size_t OFF_XR   = OFF_XT + (size_t)BB*CCH*LP*2;       // [176][32][512] bf16
static constexpr size_t OFF_XI   = OFF_XR + (size_t)TP*BB*CCH*2;       // [176][32][512] bf16
static constexpr size_t OFF_YR   = OFF_XI + (size_t)TP*BB*CCH*2;       // [32][192][512] bf16 (as u16)
static constexpr size_t OFF_YI   = OFF_YR + (size_t)BB*KP*CCH*2;       // [32][192][512] bf16 (as u16)

__device__ __forceinline__ unsigned short f2bf(float f){
  return __builtin_bit_cast(unsigned short, (__bf16)f);
}

__device__ __forceinline__ bf16x8 cvt8(float4 lo, float4 hi){
  bf16x8 r;
  r[0]=(__bf16)lo.x; r[1]=(__bf16)lo.y; r[2]=(__bf16)lo.z; r[3]=(__bf16)lo.w;
  r[4]=(__bf16)hi.x; r[5]=(__bf16)hi.y; r[6]=(__bf16)hi.z; r[7]=(__bf16)hi.w;
  return r;
}

__device__ __forceinline__ bf16x8 cvt8v(f32x4 lo, f32x4 hi){
  bf16x8 r;
  r[0]=(__bf16)lo[0]; r[1]=(__bf16)lo[1]; r[2]=(__bf16)lo[2]; r[3]=(__bf16)lo[3];
  r[4]=(__bf16)hi[0]; r[5]=(__bf16)hi[1]; r[6]=(__bf16)hi[2]; r[7]=(__bf16)hi[3];
  return r;
}

__device__ __forceinline__ f32x4 mfma16(bf16x8 a, bf16x8 b, f32x4 c){
  return __builtin_amdgcn_mfma_f32_16x16x32_bf16(a, b, c, 0, 0, 0);
}

typedef __attribute__((address_space(3))) unsigned lds_u32;
typedef __attribute__((address_space(1))) const unsigned g_u32;
// async global->LDS DMA, 16 B per lane; LDS dest = uniform base + lane*16
__device__ __forceinline__ void gll16(const void* g, void* l){
  __builtin_amdgcn_global_load_lds((g_u32*)g, (lds_u32*)l, 16, 0, 0);
}

// ---------------- P1: coef softmax + twiddle tables ----------------
__global__ __launch_bounds__(256) void prep_tables(const float* __restrict__ wts, char* ws){
  float* coef = (float*)(ws + OFF_COEF);
  unsigned short* Fc  = (unsigned short*)(ws + OFF_FC);
  unsigned short* Fs  = (unsigned short*)(ws + OFF_FS);
  unsigned short* Cc  = (unsigned short*)(ws + OFF_CCOS);
  unsigned short* Cs  = (unsigned short*)(ws + OFF_CSIN);
  const float PI2_N = 6.283185307179586f / (float)NN;
  const float inv_sqrt_n = 0.05455447255899809f;  // 1/sqrt(336)

  if (blockIdx.x == 0){
    __shared__ float red[256];
    int tid = threadIdx.x;
    float v = (tid < T_FREQ) ? wts[tid] : -1e30f;
    red[tid] = v; __syncthreads();
    for (int s = 128; s > 0; s >>= 1){ if (tid < s) red[tid] = fmaxf(red[tid], red[tid+s]); __syncthreads(); }
    float mx = red[0]; __syncthreads();
    float e = (tid < T_FREQ) ? expf(v - mx) : 0.f;
    red[tid] = e; __syncthreads();
    for (int s = 128; s > 0; s >>= 1){ if (tid < s) red[tid] += red[tid+s]; __syncthreads(); }
    float ssum = red[0];
    if (tid < T_FREQ){
      float sc = (tid == 0 || tid == T_FREQ-1) ? 1.f : 2.f;
      coef[tid] = (e / ssum) * sc * inv_sqrt_n;
    }
    return;
  }
  int gid = (blockIdx.x - 1) * 256 + threadIdx.x;
  int stride = (gridDim.x - 1) * 256;
  for (int e = gid; e < TP*LP; e += stride){
    int i = e / LP, l = e % LP;
    float c = 0.f, s = 0.f;
    if (l < NN){
      int m = (i * l) % NN;
      float sv, cv; sincosf(PI2_N * (float)m, &sv, &cv);
      c = cv * inv_sqrt_n; s = -sv * inv_sqrt_n;
    }
    Fc[e] = f2bf(c); Fs[e] = f2bf(s);
  }
  for (int e = gid; e < NN*KP; e += stride){
    int l = e / KP, i = e % KP;
    float c = 0.f, s = 0.f;
    if (i < T_FREQ){
      int m = (i * l) % NN;
      float sv, cv; sincosf(PI2_N * (float)m, &sv, &cv);
      c = cv; s = -sv;
    }
    Cc[e] = f2bf(c); Cs[e] = f2bf(s);
  }
}

// ---------------- P2: x [b][l][c] f32 -> x_t [b][c][l] bf16 (l zero-padded to 352) ----------------
__global__ __launch_bounds__(256) void transpose_x(const float* __restrict__ x, char* ws){
  unsigned short* xt = (unsigned short*)(ws + OFF_XT);
  __shared__ float tile[32][33];
  int bid = blockIdx.x;
  int b  = bid / (11*16);
  int rm = bid % (11*16);
  int lt = rm / 16, ct = rm % 16;
  int tx = threadIdx.x & 31, ty = threadIdx.x >> 5;   // 32 x 8
  #pragma unroll
  for (int k = 0; k < 4; ++k){
    int l = lt*32 + ty + k*8;
    int c = ct*32 + tx;
    float v = (l < NN) ? x[((size_t)b*NN + l)*CCH + c] : 0.f;
    tile[ty + k*8][tx] = v;
  }
  __syncthreads();
  #pragma unroll
  for (int k = 0; k < 4; ++k){
    int crow = ct*32 + ty + k*8;
    int lcol = lt*32 + tx;
    xt[((size_t)b*CCH + crow)*LP + lcol] = f2bf(tile[tx][ty + k*8]);
  }
}

// ---------------- Stage A: rfft as GEMM, M-split 2-way ----------------
__global__ __launch_bounds__(256) void stage_rfft(char* ws){
  const unsigned short* xt = (const unsigned short*)(ws + OFF_XT);
  const unsigned short* Fc = (const unsigned short*)(ws + OFF_FC);
  const unsigned short* Fs = (const unsigned short*)(ws + OFF_FS);
  unsigned short* xr = (unsigned short*)(ws + OFF_XR);
  unsigned short* xi = (unsigned short*)(ws + OFF_XI);

  int bid = blockIdx.x;
  int b  = bid >> 4;
  int rm = bid & 15;
  int c0 = (rm & 7) * 64;
  int mh = rm >> 3;
  int mbase = mh * 5;                 // tiles mbase..mbase+5; tile 5 duplicated (identical writes)
  int tid = threadIdx.x, lane = tid & 63, wv = tid >> 6;
  int kg = lane >> 4, ln = lane & 15;
  int c = c0 + wv*16 + ln;

  f32x4 aR[6], aI[6];
  #pragma unroll
  for (int m = 0; m < 6; ++m){ aR[m] = (f32x4){0,0,0,0}; aI[m] = (f32x4){0,0,0,0}; }

  const unsigned short* xrow = xt + ((size_t)b*CCH + c)*LP;
  for (int kk = 0; kk < 11; ++kk){
    int ko = kk*32 + kg*8;
    bf16x8 bx = *(const bf16x8*)(xrow + ko);
    #pragma unroll
    for (int m = 0; m < 6; ++m){
      bf16x8 fc = *(const bf16x8*)(Fc + (size_t)((mbase+m)*16 + ln)*LP + ko);
      bf16x8 fs = *(const bf16x8*)(Fs + (size_t)((mbase+m)*16 + ln)*LP + ko);
      aR[m] = mfma16(fc, bx, aR[m]);
      aI[m] = mfma16(fs, bx, aI[m]);
    }
  }
  int rbase = kg*4;
  #pragma unroll
  for (int m = 0; m < 6; ++m){
    #pragma unroll
    for (int r = 0; r < 4; ++r){
      int i = (mbase+m)*16 + rbase + r;
      size_t off = ((size_t)i*BB + b)*CCH + c;
      xr[off] = f2bf(aR[m][r]);
      xi[off] = f2bf(aI[m][r]);
    }
  }
}

// ---------------- Stage B v4: async global_load_lds staging, f32 LDS, 2x16KB quarter pipeline ----------------
// Block = (freq i, 16-out tile ot). Grid 169*32. 4 waves: (mb = batch-half, part = R/I).
// Staging map: chunk c = wv*4 + j covers part p=c>>3, rows r=(c&7)*2+{0,1}, one K-quarter.
// LDS dest is linear (lane*16); swizzle applied on the GLOBAL source granule: G = (lane&31) ^ (r&7).
// Read side: physical granule P = (kkl*8 + kg*2 + s) ^ (ln&7)  -> conflict-free b128 reads.
__global__ __launch_bounds__(256, 5) void stage_cgemm(const float* __restrict__ Wr, const float* __restrict__ Wi,
                                                      const float* __restrict__ br, const float* __restrict__ bi,
                                                      char* ws){
  const unsigned short* xr = (const unsigned short*)(ws + OFF_XR);
  const unsigned short* xi = (const unsigned short*)(ws + OFF_XI);
  const float* coef = (const float*)(ws + OFF_COEF);
  unsigned short* yr = (unsigned short*)(ws + OFF_YR);
  unsigned short* yi = (unsigned short*)(ws + OFF_YI);

  __shared__ float sW[2][2][16][QK];   // [buf][part][row][k] f32, 2 x 16 KB

  int bid = blockIdx.x;
  int i  = bid >> 5;
  int ot = bid & 31;
  int tid = threadIdx.x, lane = tid & 63, wv = tid >> 6;
  int kg = lane >> 4, ln = lane & 15;

  // per-(wave,j) global source pointers for the 4 staging chunks
  const float* gsrc[4];
  float* ldst0[4];
  float* ldst1[4];
  #pragma unroll
  for (int j = 0; j < 4; ++j){
    int c = wv*4 + j;
    int p = c >> 3;
    int r = ((c & 7) << 1) + (lane >> 5);
    int G = (lane & 31) ^ (r & 7);
    const float* base = p ? Wi : Wr;
    gsrc[j] = base + ((size_t)i*CCH + ot*16 + r)*CCH + G*4;
    ldst0[j] = &sW[0][p][(c & 7) << 1][0];
    ldst1[j] = &sW[1][p][(c & 7) << 1][0];
  }

  int mb = wv & 1, part = wv >> 1;
  f32x4 acc = (f32x4){0,0,0,0};
  const unsigned short* xa = xr + (size_t)(i*BB + mb*16 + ln)*CCH;
  const unsigned short* xb = xi + (size_t)(i*BB + mb*16 + ln)*CCH;

  // prologue: stage quarter 0 into buf 0
  #pragma unroll
  for (int j = 0; j < 4; ++j) gll16(gsrc[j], ldst0[j]);
  asm volatile("s_waitcnt vmcnt(0)" ::: "memory");
  __syncthreads();

  #pragma unroll
  for (int q = 0; q < 4; ++q){
    const int cur = q & 1;
    // async stage of next quarter into the other buffer
    if (q < 3){
      #pragma unroll
      for (int j = 0; j < 4; ++j)
        gll16(gsrc[j] + (size_t)(q+1)*QK, cur ? ldst0[j] : ldst1[j]);
    }
    // compute current quarter
    const float* wr_row = &sW[cur][0][ln][0];
    const float* wi_row = &sW[cur][1][ln][0];
    #pragma unroll
    for (int kkl = 0; kkl < 4; ++kkl){
      int ko = q*QK + kkl*32 + kg*8;
      bf16x8 ar = *(const bf16x8*)(xa + ko);
      bf16x8 ai = *(const bf16x8*)(xb + ko);
      int g0 = ((kkl*8 + kg*2 + 0) ^ (ln & 7)) * 4;
      int g1 = ((kkl*8 + kg*2 + 1) ^ (ln & 7)) * 4;
      f32x4 w0 = *(const f32x4*)(wr_row + g0);
      f32x4 w1 = *(const f32x4*)(wr_row + g1);
      f32x4 v0 = *(const f32x4*)(wi_row + g0);
      f32x4 v1 = *(const f32x4*)(wi_row + g1);
      bf16x8 wr8 = cvt8v(w0, w1);
      bf16x8 wi8 = cvt8v(v0, v1);
      bf16x8 nwi = __builtin_bit_cast(bf16x8, (s16x8)(__builtin_bit_cast(s16x8, wi8) ^ (short)0x8000));
      bf16x8 b1 = part ? wi8 : wr8;
      bf16x8 b2 = part ? wr8 : nwi;
      acc = mfma16(ar, b1, acc);     // part R: xr*Wr   | part I: xr*Wi
      acc = mfma16(ai, b2, acc);     // part R: -xi*Wi  | part I: xi*Wr
    }
    if (q < 3){
      asm volatile("s_waitcnt vmcnt(0)" ::: "memory");
      __syncthreads();
    }
  }

  int o = ot*16 + ln;
  float cf = coef[i];
  float bias = (part ? bi : br)[(size_t)i*CCH + o];
  unsigned short* yp = part ? yi : yr;
  #pragma unroll
  for (int r = 0; r < 4; ++r){
    int bb = mb*16 + kg*4 + r;
    yp[((size_t)bb*KP + i)*CCH + o] = f2bf((acc[r] + bias) * cf);
  }
}

// ---------------- Stage C: irfft projection, M-split 2-way ----------------
__global__ __launch_bounds__(256) void stage_irfft(const char* ws_c, float* __restrict__ out){
  const char* ws = ws_c;
  const unsigned short* Cc = (const unsigned short*)(ws + OFF_CCOS);
  const unsigned short* Cs = (const unsigned short*)(ws + OFF_CSIN);
  const unsigned short* yr = (const unsigned short*)(ws + OFF_YR);
  const unsigned short* yi = (const unsigned short*)(ws + OFF_YI);

  __shared__ unsigned short lr[64][40];
  __shared__ unsigned short li[64][40];

  int bid = blockIdx.x;
  int b  = bid >> 4;
  int rm = bid & 15;
  int c0 = (rm & 7) * 64;
  int mh = rm >> 3;
  int mbase = mh * 10;                // tiles mbase..mbase+10; tile 10 duplicated (identical writes)
  int tid = threadIdx.x, lane = tid & 63, wv = tid >> 6;
  int kg = lane >> 4, ln = lane & 15;

  f32x4 acc[11];
  #pragma unroll
  for (int m = 0; m < 11; ++m) acc[m] = (f32x4){0,0,0,0};

  for (int kk = 0; kk < 6; ++kk){
    if (kk) __syncthreads();
    #pragma unroll
    for (int q = 0; q < 8; ++q){
      int idx = q*256 + tid;
      int ir = idx >> 6, cc = idx & 63;
      int i = kk*32 + ir;
      unsigned short vr = 0, vi = 0;
      if (i < T_FREQ){
        size_t off = ((size_t)b*KP + i)*CCH + c0 + cc;
        vr = yr[off]; vi = yi[off];
      }
      lr[cc][ir] = vr;
      li[cc][ir] = vi;
    }
    __syncthreads();
    int ko = kk*32 + kg*8;
    bf16x8 blr = *(const bf16x8*)(&lr[wv*16 + ln][kg*8]);
    bf16x8 bli = *(const bf16x8*)(&li[wv*16 + ln][kg*8]);
    #pragma unroll
    for (int m = 0; m < 11; ++m){
      bf16x8 ac = *(const bf16x8*)(Cc + (size_t)((mbase+m)*16 + ln)*KP + ko);
      bf16x8 as = *(const bf16x8*)(Cs + (size_t)((mbase+m)*16 + ln)*KP + ko);
      acc[m] = mfma16(ac, blr, acc[m]);
      acc[m] = mfma16(as, bli, acc[m]);
    }
  }

  int cdst = c0 + wv*16 + ln;
  #pragma unroll
  for (int m = 0; m < 11; ++m){
    #pragma unroll
    for (int r = 0; r < 4; ++r){
      int l = (mbase+m)*16 + kg*4 + r;
      out[((size_t)b*NN + l)*CCH + cdst] = acc[m][r];
    }
  }
}

extern "C" void kernel_launch(void* const* d_in, const int* in_sizes, int n_in,
                              void* d_out, int out_size, void* d_ws, size_t ws_size,
                              hipStream_t stream){
  const float* x   = (const float*)d_in[0];
  const float* Wr  = (const float*)d_in[1];
  const float* Wi  = (const float*)d_in[2];
  const float* br  = (const float*)d_in[3];
  const float* bi  = (const float*)d_in[4];
  const float* wts = (const float*)d_in[5];
  char* ws = (char*)d_ws;

  prep_tables<<<257, 256, 0, stream>>>(wts, ws);
  transpose_x<<<32*11*16, 256, 0, stream>>>(x, ws);
  stage_rfft<<<512, 256, 0, stream>>>(ws);
  stage_cgemm<<<T_FREQ*32, 256, 0, stream>>>(Wr, Wi, br, bi, ws);
  stage_irfft<<<512, 256, 0, stream>>>(ws, (float*)d_out);
}